// Round 8
// baseline (263.215 us; speedup 1.0000x reference)
//
#include <hip/hip_runtime.h>
#include <hip/hip_bf16.h>

#define NB 512
#define NT 256
#define NV 27
#define NE 64
#define NH 128

typedef float v2f __attribute__((ext_vector_type(2)));

__device__ __forceinline__ v2f mk2(float a, float b) { v2f r; r.x = a; r.y = b; return r; }
__device__ __forceinline__ v2f pkfma(v2f a, v2f b, v2f c) {
    return __builtin_elementwise_fma(a, b, c);   // -> v_pk_fma_f32
}

__device__ __forceinline__ float fast_tanh(float x) {
    // tanh(x) = 1 - 2/(2^(2x*log2e)+1); exact at both saturation ends (inf/0).
    float e = __builtin_amdgcn_exp2f(x * 2.885390081777927f);
    return fmaf(-2.0f, __builtin_amdgcn_rcpf(e + 1.0f), 1.0f);
}

// x + x(lane^mask) via DPP quad_perm, full-rate VALU (no DS ops)
template<int CTRL>
__device__ __forceinline__ float dpp_xadd(float x) {
    int t = __builtin_amdgcn_mov_dpp(__float_as_int(x), CTRL, 0xF, 0xF, true);
    return x + __int_as_float(t);
}
// x + x(lane^32) via v_permlane32_swap (gfx950). REGISTER-AIRTIGHT form:
// duplicate inside the asm into two distinct early-clobber outputs (the "+v","+v"
// same-value form let the allocator coalesce them -> in-place half-swap bug).
__device__ __forceinline__ float permlane32_sum(float x) {
    float a, b;
    asm("v_mov_b32 %0, %2\n\t"
        "v_mov_b32 %1, %2\n\t"
        "v_permlane32_swap_b32 %0, %1"
        : "=&v"(a), "=&v"(b) : "v"(x));
    return a + b;
}
// all-reduce over the 8 split-k lanes (lane bits {0,1,5}); result in ALL lanes
__device__ __forceinline__ float red8(float x) {
    x = dpp_xadd<0xB1>(x);    // xor 1
    x = dpp_xadd<0x4E>(x);    // xor 2
    return permlane32_sum(x); // xor 32
}
// reduce-SCATTER over lane bits {0,1,5}: inputs = partials for cols j0..j0+3 of
// this lane's k-chunk; output = FULL sum for col jc = j0 + 2*b0 + b1.
__device__ __forceinline__ float rs8(float ax, float ay, float az, float aw,
                                     bool b0, bool b1) {
    float A = dpp_xadd<0xB1>(ax);     // col j0+0 over b0-pairs
    float B = dpp_xadd<0xB1>(ay);
    float C = dpp_xadd<0xB1>(az);
    float D = dpp_xadd<0xB1>(aw);
    float v0 = b0 ? C : A;            // col j0 + 2*b0
    float v1 = b0 ? D : B;            // col j0 + 2*b0 + 1
    v0 = dpp_xadd<0x4E>(v0);          // over b1-pairs
    v1 = dpp_xadd<0x4E>(v1);
    float v = b1 ? v1 : v0;           // col j0 + 2*b0 + b1
    return permlane32_sum(v);         // over b5-pairs
}

// embW[v][j] = b[j] + sum_e emb[v][e] * W[e][j]   (x_t @ W == embW[id_t])
__global__ void embw_kernel(const float* __restrict__ emb,
                            const float* __restrict__ W,
                            const float* __restrict__ bias,
                            float* __restrict__ out) {
    const int v = blockIdx.x;
    const int j = threadIdx.x;
    float acc = bias[j];
    #pragma unroll
    for (int e = 0; e < NE; ++e)
        acc = fmaf(emb[v * NE + e], W[e * NH + j], acc);
    out[v * NH + j] = acc;
}

// Ring layout: h chunk s (cols 16s..16s+15) at float offset 20*s (16 + 4 pad)
// -> the 8 split-k broadcast b128 reads cover all 32 banks exactly once.
#define RING_W 168

// ---- U fragment as k-PAIR float2s, one set of 8 per column (transposed) ----
#define LDC(P, C, OFF) \
    C##0 = mk2((P)[(16*s+ 0)*NH + j0+(OFF)], (P)[(16*s+ 1)*NH + j0+(OFF)]); \
    C##1 = mk2((P)[(16*s+ 2)*NH + j0+(OFF)], (P)[(16*s+ 3)*NH + j0+(OFF)]); \
    C##2 = mk2((P)[(16*s+ 4)*NH + j0+(OFF)], (P)[(16*s+ 5)*NH + j0+(OFF)]); \
    C##3 = mk2((P)[(16*s+ 6)*NH + j0+(OFF)], (P)[(16*s+ 7)*NH + j0+(OFF)]); \
    C##4 = mk2((P)[(16*s+ 8)*NH + j0+(OFF)], (P)[(16*s+ 9)*NH + j0+(OFF)]); \
    C##5 = mk2((P)[(16*s+10)*NH + j0+(OFF)], (P)[(16*s+11)*NH + j0+(OFF)]); \
    C##6 = mk2((P)[(16*s+12)*NH + j0+(OFF)], (P)[(16*s+13)*NH + j0+(OFF)]); \
    C##7 = mk2((P)[(16*s+14)*NH + j0+(OFF)], (P)[(16*s+15)*NH + j0+(OFF)]);
#define LDALL(P) LDC(P,ua,0) LDC(P,ub,1) LDC(P,uc,2) LDC(P,ud,3)

// One-time pin (OUTSIDE the loops): anchors fragments as materialized values so
// the compiler cannot re-load them from global inside the step loops. Hoisted
// from per-step (r6) to once-per-phase: removes any per-step copy trains if the
// fragments are AGPR-homed. Placement is the ONLY delta vs the passing r6.
#define PIN8(C) asm("" : "+v"(C##0),"+v"(C##1),"+v"(C##2),"+v"(C##3), \
                        "+v"(C##4),"+v"(C##5),"+v"(C##6),"+v"(C##7));
#define PINU PIN8(ua) PIN8(ub) PIN8(uc) PIN8(ud)

// per-column dot over this lane's 16 k: 8 pk-FMA in 2 chains + merge
#define DOTC(RES, C) { \
    v2f q1 = p0 * C##0; \
    q1 = pkfma(p1, C##1, q1); q1 = pkfma(p2, C##2, q1); q1 = pkfma(p3, C##3, q1); \
    v2f q2 = p4 * C##4; \
    q2 = pkfma(p5, C##5, q2); q2 = pkfma(p6, C##6, q2); q2 = pkfma(p7, C##7, q2); \
    v2f qq = q1 + q2; RES = qq.x + qq.y; }

// load this lane's h chunk (16 k) from ring slot RD as float4s, pair for pkfma
#define HLOAD(RD) \
    const float4* hp4 = (const float4*)(&ring[RD][rdo]); \
    const float4 h0 = hp4[0], h1 = hp4[1], h2 = hp4[2], h3 = hp4[3]; \
    const v2f p0 = mk2(h0.x,h0.y), p1 = mk2(h0.z,h0.w), \
              p2 = mk2(h1.x,h1.y), p3 = mk2(h1.z,h1.w), \
              p4 = mk2(h2.x,h2.y), p5 = mk2(h2.z,h2.w), \
              p6 = mk2(h3.x,h3.y), p7 = mk2(h3.z,h3.w);

#define RECUR(WR, XE) \
    float cx, cy, cz, cw; \
    DOTC(cx, ua) DOTC(cy, ub) DOTC(cz, uc) DOTC(cw, ud) \
    const float xs = rs8(cx, cy, cz, cw, b0, b1); \
    const float h = fast_tanh(xs + (XE)); \
    if (wlane) ring[WR][woff] = h; \
    __syncthreads();

#define ESTEP(RD, WR, T) { \
    HLOAD(RD) \
    const float xe = xen; \
    { const int id2 = ids_lds[((T) + 1) & (NT - 1)]; \
      xen = embw_lds[(id2 << 7) + jc]; } \
    RECUR(WR, xe) }

#define LOGITS(T) { \
    v2f L1 = p0 * wp0; \
    L1 = pkfma(p1, wp1, L1); L1 = pkfma(p2, wp2, L1); L1 = pkfma(p3, wp3, L1); \
    v2f L2 = p4 * wp4; \
    L2 = pkfma(p5, wp5, L2); L2 = pkfma(p6, wp6, L2); L2 = pkfma(p7, wp7, L2); \
    v2f LL = L1 + L2; \
    const float lacc = red8(LL.x + LL.y); \
    if (lstore) out[((size_t)b * NT + ((T) - 1)) * NV + vv] = lacc + bov; }

#define DSTEP(RD, WR, T) { \
    HLOAD(RD) \
    const float xe = xdn; \
    { const int id2 = ids_lds[NT + (((T) + 1) & (NT - 1))]; \
      xdn = embw_lds[NV * NH + (id2 << 7) + jc]; } \
    LOGITS(T) \
    RECUR(WR, xe) }

__global__ __attribute__((amdgpu_waves_per_eu(2, 2))) __launch_bounds__(256)
void rnn_kernel(
    const int* __restrict__ enc_ids,
    const int* __restrict__ dec_ids,
    const float* __restrict__ U_enc,
    const float* __restrict__ U_dec,
    const float* __restrict__ embw,   // [2][NV][NH]
    const float* __restrict__ W_out,  // [NH][NV]
    const float* __restrict__ b_out,  // [NV]
    float* __restrict__ out)          // [NB][NT][NV]
{
    __shared__ __align__(16) float ring[2][RING_W];
    __shared__ __align__(16) float embw_lds[2 * NV * NH];
    __shared__ int ids_lds[2 * NT];

    const int tid = threadIdx.x;
    const int b   = blockIdx.x;                 // one batch row per block
    const int l   = tid & 63;                   // lane
    const int w   = tid >> 6;                   // wave 0..3
    const int s   = (l & 3) | ((l >> 5) << 2);  // split-k chunk (lane bits 0,1,5)
    const int cg  = (l >> 2) & 7;               // col-group (lane bits 2,3,4)
    const int j0  = 32 * w + 4 * cg;
    const bool b0 = (l & 1) != 0;
    const bool b1 = (l & 2) != 0;
    const int jc  = j0 + 2 * (int)b0 + (int)b1; // this lane's output column
    const int woff = 20 * (jc >> 4) + (jc & 15);
    const int rdo  = 20 * s;
    const bool wlane = (l < 32);                // bit5-duplicates don't write

    // ---- stage LDS ----
    for (int i = tid; i < 2 * NV * NH / 4; i += 256)
        ((float4*)embw_lds)[i] = ((const float4*)embw)[i];
    ids_lds[tid]      = enc_ids[b * NT + tid];
    ids_lds[NT + tid] = dec_ids[b * NT + tid];
    if (tid < RING_W) ring[0][tid] = 0.0f;      // h0 = 0

    // ---- U_enc fragment: 4 cols x 8 k-pairs, named v2f registers ----
    v2f ua0, ua1, ua2, ua3, ua4, ua5, ua6, ua7;
    v2f ub0, ub1, ub2, ub3, ub4, ub5, ub6, ub7;
    v2f uc0, uc1, uc2, uc3, uc4, uc5, uc6, uc7;
    v2f ud0, ud1, ud2, ud3, ud4, ud5, ud6, ud7;
    LDALL(U_enc)
    PINU   // once per phase: anchor in registers before the loop

    __syncthreads();

    // =========================== encoder: 256 steps ===========================
    float xen = embw_lds[(ids_lds[0] << 7) + jc];
    #pragma unroll 1
    for (int t = 0; t < NT; t += 2) {
        ESTEP(0, 1, t)
        ESTEP(1, 0, t + 1)
    }

    // ======================= switch to decoder weights =======================
    LDALL(U_dec)
    const int  vv  = 8 * w + cg;                // 0..31
    const bool vok = (vv < NV);
    v2f wp0, wp1, wp2, wp3, wp4, wp5, wp6, wp7;
    {
        const float* Wp = W_out + 16 * s * NV + (vok ? vv : 0);
        wp0 = mk2(Wp[ 0*NV], Wp[ 1*NV]);  wp1 = mk2(Wp[ 2*NV], Wp[ 3*NV]);
        wp2 = mk2(Wp[ 4*NV], Wp[ 5*NV]);  wp3 = mk2(Wp[ 6*NV], Wp[ 7*NV]);
        wp4 = mk2(Wp[ 8*NV], Wp[ 9*NV]);  wp5 = mk2(Wp[10*NV], Wp[11*NV]);
        wp6 = mk2(Wp[12*NV], Wp[13*NV]);  wp7 = mk2(Wp[14*NV], Wp[15*NV]);
    }
    PINU PIN8(wp)   // once per phase: anchor decoder fragments
    const float bov = vok ? b_out[vok ? vv : 0] : 0.0f;
    const bool lstore = vok && ((l & 3) == 0) && (l < 32);

    // ================= decoder: 256 steps + logits tail =================
    // iter t: recurrence consumes dec input t; logits of the state READ this
    // iter (= dec_hs[t-1]) are emitted for t>=1; tail iter emits dec_hs[255].
    float xdn = embw_lds[NV * NH + (ids_lds[NT] << 7) + jc];
    {   // t = 0: recurrence only (state read is the encoder final state)
        HLOAD(0)
        const float xe = xdn;
        { const int id2 = ids_lds[NT + 1];
          xdn = embw_lds[NV * NH + (id2 << 7) + jc]; }
        RECUR(1, xe)
    }
    #pragma unroll 1
    for (int t = 1; t < NT - 1; t += 2) {
        DSTEP(1, 0, t)
        DSTEP(0, 1, t + 1)
    }
    DSTEP(1, 0, NT - 1)
    {   // tail: logits for dec step NT-1 from ring[0]
        HLOAD(0)
        LOGITS(NT)
    }
}

extern "C" void kernel_launch(void* const* d_in, const int* in_sizes, int n_in,
                              void* d_out, int out_size, void* d_ws, size_t ws_size,
                              hipStream_t stream) {
    const int*   enc_ids = (const int*)  d_in[0];
    const int*   dec_ids = (const int*)  d_in[1];
    const float* emb     = (const float*)d_in[2];
    const float* W_enc   = (const float*)d_in[3];
    const float* U_enc   = (const float*)d_in[4];
    const float* b_enc   = (const float*)d_in[5];
    const float* W_dec   = (const float*)d_in[6];
    const float* U_dec   = (const float*)d_in[7];
    const float* b_dec   = (const float*)d_in[8];
    const float* W_out   = (const float*)d_in[9];
    const float* b_out   = (const float*)d_in[10];
    float* outp = (float*)d_out;
    float* wsf  = (float*)d_ws;   // [2][NV][NH] = 27.6 KB

    embw_kernel<<<NV, NH, 0, stream>>>(emb, W_enc, b_enc, wsf);
    embw_kernel<<<NV, NH, 0, stream>>>(emb, W_dec, b_dec, wsf + NV * NH);
    rnn_kernel<<<NB, 256, 0, stream>>>(enc_ids, dec_ids, U_enc, U_dec,
                                       wsf, W_out, b_out, outp);
}